// Round 2
// baseline (363.070 us; speedup 1.0000x reference)
//
#include <hip/hip_runtime.h>
#include <stdint.h>

// Problem constants
#define N_B   512
#define D_K   512
#define C_N   50000
#define BN    64
#define NCB   782          // ceil(C_N/BN)
#define C_PAD (NCB * BN)   // 50048

#define S_SCALE 30.0f
#define COS_Mc  0.87758256189037276f
#define SIN_Mc  0.47942553860420301f
#define TH_Cc  (-0.87758256189037276f)
#define MM_Cc   0.23971276930210156f
#define SHIFT   30.0f      // all outputs <= 30, so exp(o-30) never overflows

typedef __attribute__((ext_vector_type(8))) __bf16 bf16x8;
typedef __attribute__((ext_vector_type(4))) float  f32x4;

__device__ __forceinline__ unsigned short f2bf(float f) {
    union { float f; unsigned u; } v; v.f = f;
    unsigned r = v.u + 0x7FFFu + ((v.u >> 16) & 1u);   // RNE
    return (unsigned short)(r >> 16);
}

// x prep: one wave per row, exact fp32 inverse L2 norm + bf16 convert.
__global__ __launch_bounds__(256) void prep_x_kernel(
        const float* __restrict__ src, unsigned short* __restrict__ dstb,
        float* __restrict__ inv)
{
    int wave = threadIdx.x >> 6, lane = threadIdx.x & 63;
    int row = blockIdx.x * 4 + wave;
    const float4* s4 = (const float4*)(src + (size_t)row * D_K) + lane * 2;
    float4 a = s4[0], b = s4[1];
    float ss = a.x*a.x + a.y*a.y + a.z*a.z + a.w*a.w
             + b.x*b.x + b.y*b.y + b.z*b.z + b.w*b.w;
    #pragma unroll
    for (int off = 32; off >= 1; off >>= 1) ss += __shfl_xor(ss, off, 64);
    if (lane == 0) inv[row] = 1.0f / fmaxf(sqrtf(ss), 1e-12f);
    uint4 o;
    o.x = (unsigned)f2bf(a.x) | ((unsigned)f2bf(a.y) << 16);
    o.y = (unsigned)f2bf(a.z) | ((unsigned)f2bf(a.w) << 16);
    o.z = (unsigned)f2bf(b.x) | ((unsigned)f2bf(b.y) << 16);
    o.w = (unsigned)f2bf(b.z) | ((unsigned)f2bf(b.w) << 16);
    *(uint4*)(dstb + (size_t)row * D_K + lane * 8) = o;
}

// Fused GEMM: per block, 64 classes x 256 rows, K=512 fully unrolled.
// W fp32 read once from HBM -> bf16 swizzled LDS; invw computed in-kernel
// from the bf16 copy; A fragments read straight from global (xb is 512 KB,
// fully L2-resident). Zero barriers in the K-loop.
// Ws swizzle: element (col,k) at ushort index col*512 + ((k>>3)^(col&7))*8 + (k&7)
__global__ __launch_bounds__(256, 2) void gemm2_kernel(
        const unsigned short* __restrict__ xb, const float* __restrict__ w,
        const float* __restrict__ invx, const int* __restrict__ labels,
        float* __restrict__ out, float* __restrict__ s_part)
{
    const int half = blockIdx.x;           // row half: 0/1 (fast dim -> same cb concurrent)
    const int cb   = blockIdx.y;           // 0..781
    const int c0   = cb * BN;
    const int rbase = half * 256;
    const int tid  = threadIdx.x;
    const int lane = tid & 63, wave = tid >> 6;
    const int l15  = lane & 15, q = lane >> 4;

    __shared__ __align__(16) unsigned short Ws[BN * D_K];   // 64 KB
    __shared__ float s_invw[BN];
    __shared__ float s_invx[256];
    __shared__ int   s_lab[256];

    s_invx[tid] = invx[rbase + tid];
    s_lab[tid]  = labels[rbase + tid];

    // ---- Phase 1: stage W fp32 -> bf16 LDS (coalesced, swizzled dest) ----
    #pragma unroll 4
    for (int i = 0; i < 32; i++) {
        int flat = i * 1024 + tid * 4;          // 256 thr x 4 floats = 1024/iter
        int col = flat >> 9, k = flat & 511;
        int gcol = c0 + col;
        float4 v = make_float4(0.f, 0.f, 0.f, 0.f);
        if (gcol < C_N) v = *(const float4*)(w + (size_t)gcol * D_K + k);
        uint2 p;
        p.x = (unsigned)f2bf(v.x) | ((unsigned)f2bf(v.y) << 16);
        p.y = (unsigned)f2bf(v.z) | ((unsigned)f2bf(v.w) << 16);
        int idx = col * D_K + (((k >> 3) ^ (col & 7)) << 3) + (k & 7);
        *(uint2*)(Ws + idx) = p;
    }
    __syncthreads();

    // ---- Phase 1b: invw from the bf16 LDS copy (16 cols per wave) ----
    for (int p = 0; p < 16; p++) {
        int c = wave * 16 + p;
        int addr = c * D_K + (((lane ^ (c & 7)) & 63) << 3);  // chunk = lane
        uint4 u = *(const uint4*)(Ws + addr);
        float ss = 0.f;
        #pragma unroll
        for (int j = 0; j < 4; j++) {
            unsigned word = (&u.x)[j];
            float a = __uint_as_float(word << 16);
            float b = __uint_as_float(word & 0xffff0000u);
            ss += a * a + b * b;
        }
        #pragma unroll
        for (int off = 32; off >= 1; off >>= 1) ss += __shfl_xor(ss, off, 64);
        if (lane == 0) s_invw[c] = 1.0f / fmaxf(sqrtf(ss), 1e-12f);
    }
    __syncthreads();

    // ---- Phase 2: K-loop, no barriers ----
    const int r0 = rbase + wave * 64;
    f32x4 zero4 = {0.f, 0.f, 0.f, 0.f};
    f32x4 acc[4][4];
    #pragma unroll
    for (int i = 0; i < 4; i++)
        #pragma unroll
        for (int j = 0; j < 4; j++) acc[i][j] = zero4;

    const unsigned short* Abase = xb + (size_t)(r0 + l15) * D_K + q * 8;

    #pragma unroll
    for (int ks = 0; ks < 16; ks++) {
        bf16x8 af[4], bfr[4];
        #pragma unroll
        for (int mi = 0; mi < 4; mi++)
            af[mi] = *(const bf16x8*)(Abase + mi * 16 * D_K + ks * 32);
        #pragma unroll
        for (int ni = 0; ni < 4; ni++) {
            int nc = ni * 16 + l15;
            int ch = (ks * 4 + q) ^ (nc & 7);
            bfr[ni] = *(const bf16x8*)(Ws + nc * D_K + ch * 8);
        }
        #pragma unroll
        for (int mi = 0; mi < 4; mi++)
            #pragma unroll
            for (int ni = 0; ni < 4; ni++)
                acc[mi][ni] = __builtin_amdgcn_mfma_f32_16x16x32_bf16(
                                  af[mi], bfr[ni], acc[mi][ni], 0, 0, 0);
    }

    // ---- Epilogue: scale, margin at label col, store, exp-sum partial ----
    // C/D layout: col = lane&15, row = (lane>>4)*4 + reg
    #pragma unroll
    for (int mi = 0; mi < 4; mi++) {
        #pragma unroll
        for (int r = 0; r < 4; r++) {
            int lrow = wave * 64 + mi * 16 + q * 4 + r;    // local row 0..255
            int grow = rbase + lrow;
            float ivx = s_invx[lrow];
            int lab = s_lab[lrow];
            float es = 0.f;
            #pragma unroll
            for (int ni = 0; ni < 4; ni++) {
                int gcol = c0 + ni * 16 + l15;
                float cosv = acc[mi][ni][r] * ivx * s_invw[ni * 16 + l15];
                float o = S_SCALE * cosv;
                if (gcol == lab) {
                    float s2 = fminf(fmaxf(1.0f + 1e-7f - cosv * cosv, 0.f), 1.f);
                    float phi = cosv * COS_Mc - sqrtf(s2) * SIN_Mc;
                    if (!(cosv > TH_Cc)) phi = cosv - MM_Cc;
                    o = S_SCALE * phi;
                }
                if (gcol < C_N) {
                    out[(size_t)grow * C_N + gcol] = o;
                    es += __expf(o - SHIFT);
                }
            }
            es += __shfl_xor(es, 1, 64);
            es += __shfl_xor(es, 2, 64);
            es += __shfl_xor(es, 4, 64);
            es += __shfl_xor(es, 8, 64);
            if (l15 == 0) s_part[(size_t)cb * N_B + grow] = es;
        }
    }
}

// Merge the NCB partial exp-sums per row -> logZ -> per-row loss term.
// s_part layout [NCB][N_B] -> coalesced reads (lane = row).
__global__ void rowreduce_kernel(
        const float* __restrict__ s_part, const float* __restrict__ out,
        const int* __restrict__ labels, float* __restrict__ lossp)
{
    int b = blockIdx.x;                    // 0..7
    int r = b * 64 + (threadIdx.x & 63);
    int c = threadIdx.x >> 6;              // 0..7
    float s = 0.f;
    for (int j = c; j < NCB; j += 8) s += s_part[(size_t)j * N_B + r];
    __shared__ float pt[8][64];
    pt[c][threadIdx.x & 63] = s;
    __syncthreads();
    if (threadIdx.x < 64) {
        int row = b * 64 + threadIdx.x;
        float t = 0.f;
        #pragma unroll
        for (int cc = 0; cc < 8; cc++) t += pt[cc][threadIdx.x];
        float logZ = SHIFT + logf(t);
        lossp[row] = logZ - out[(size_t)row * C_N + labels[row]];
    }
}

__global__ void loss_kernel(const float* __restrict__ lossp, float* __restrict__ loss_out) {
    int t = threadIdx.x;   // blockDim = 256
    float v = lossp[t] + lossp[t + 256];
    #pragma unroll
    for (int off = 32; off >= 1; off >>= 1) v += __shfl_xor(v, off, 64);
    __shared__ float part[4];
    if ((t & 63) == 0) part[t >> 6] = v;
    __syncthreads();
    if (t == 0) loss_out[0] = (part[0] + part[1] + part[2] + part[3]) * (1.0f / 512.0f);
}

extern "C" void kernel_launch(void* const* d_in, const int* in_sizes, int n_in,
                              void* d_out, int out_size, void* d_ws, size_t ws_size,
                              hipStream_t stream)
{
    const float* x      = (const float*)d_in[0];
    const int*   labels = (const int*)d_in[1];
    const float* w      = (const float*)d_in[2];
    float* out = (float*)d_out;
    float* loss_out = out + (size_t)N_B * C_N;

    char* ws = (char*)d_ws;
    size_t off = 0;
    unsigned short* xb = (unsigned short*)(ws + off); off += (size_t)N_B * D_K * 2;   // 512 KB
    float* invx   = (float*)(ws + off); off += (size_t)N_B * 4;
    float* s_part = (float*)(ws + off); off += (size_t)NCB * N_B * 4;                 // 1.6 MB
    float* lossp  = (float*)(ws + off); off += (size_t)N_B * 4;

    prep_x_kernel<<<N_B / 4, 256, 0, stream>>>(x, xb, invx);
    gemm2_kernel<<<dim3(2, NCB), 256, 0, stream>>>(xb, w, invx, labels, out, s_part);
    rowreduce_kernel<<<8, 512, 0, stream>>>(s_part, out, labels, lossp);
    loss_kernel<<<1, 256, 0, stream>>>(lossp, loss_out);
}